// Round 4
// baseline (373.570 us; speedup 1.0000x reference)
//
#include <hip/hip_runtime.h>
#include <math.h>

#define DEPTH 6
#define HEADS 8
#define DIMH  64
#define BB    2
#define NN    128
#define EE    160
#define NF    127
#define DIMM  128
#define INNER 512

__device__ __forceinline__ void fma4(float4& acc, float a, const float4 w) {
    acc.x += a * w.x; acc.y += a * w.y; acc.z += a * w.z; acc.w += a * w.w;
}

// 512-thread block, reduce over each 128-thread group (2 waves); result valid
// for groups 0,1 (threads < 256). sbuf8: 8 floats.
__device__ __forceinline__ float group_reduce_128(float v, float* sbuf8) {
#pragma unroll
    for (int off = 32; off > 0; off >>= 1) v += __shfl_xor(v, off, 64);
    int w = threadIdx.x >> 6;
    if ((threadIdx.x & 63) == 0) sbuf8[w] = v;
    __syncthreads();
    int g = threadIdx.x >> 7;
    float r = sbuf8[2 * g] + sbuf8[2 * g + 1];
    __syncthreads();
    return r;
}

// LN over 128 dims + QKV projection for 2 nodes (bn0, bn0+1), 512 threads.
// nd = node value at (r = t>>7, d = t&127), valid for t<256.
// s_xn: 256 floats, s_red: 8, s_part: 12288 (48 KB).
__device__ void ln_qkv_R2(float nd, int t, int bn0, int layer,
                          const float* ln_g, const float* ln_b,
                          const float* Wq, const float* bq,
                          const float* Wkv, const float* bkv,
                          float* qb, float* kb, float* vb,
                          float* s_xn, float* s_red, float* s_part) {
    int d = t & 127;
    int r = t >> 7;
    bool own = (t < 256);
    float m   = group_reduce_128(own ? nd : 0.0f, s_red) * (1.0f / 128.0f);
    float df  = nd - m;
    float var = group_reduce_128(own ? df * df : 0.0f, s_red) * (1.0f / 128.0f);
    float xn  = df * rsqrtf(var + 1e-5f) * ln_g[layer * DIMM + d] + ln_b[layer * DIMM + d];
    if (own) s_xn[r * 128 + d] = xn;
    __syncthreads();

    int c7  = t & 127;   // output quad (4*c7..4*c7+3) within each 512-wide mat
    int kg  = t >> 7;    // 4 K-groups of 32
    int kkb = kg * 32;
    const float4* WqR  = (const float4*)(Wq  + (size_t)layer * DIMM * INNER);
    const float4* WkvR = (const float4*)(Wkv + (size_t)layer * DIMM * 2 * INNER);
    float4 q0 = {0,0,0,0}, q1 = {0,0,0,0};
    float4 k0 = {0,0,0,0}, k1 = {0,0,0,0};
    float4 v0 = {0,0,0,0}, v1 = {0,0,0,0};
#pragma unroll 8
    for (int rr = 0; rr < 32; rr++) {
        int kk = kkb + rr;
        float a0 = s_xn[kk], a1 = s_xn[128 + kk];
        float4 wq = WqR[kk * 128 + c7];
        float4 wk = WkvR[kk * 256 + c7];
        float4 wv = WkvR[kk * 256 + 128 + c7];
        fma4(q0, a0, wq); fma4(q1, a1, wq);
        fma4(k0, a0, wk); fma4(k1, a1, wk);
        fma4(v0, a0, wv); fma4(v1, a1, wv);
    }
    // partials: ((m*2 + r)*4 + kg)*512 + out
    ((float4*)(s_part + ((0 * 2 + 0) * 4 + kg) * 512))[c7] = q0;
    ((float4*)(s_part + ((0 * 2 + 1) * 4 + kg) * 512))[c7] = q1;
    ((float4*)(s_part + ((1 * 2 + 0) * 4 + kg) * 512))[c7] = k0;
    ((float4*)(s_part + ((1 * 2 + 1) * 4 + kg) * 512))[c7] = k1;
    ((float4*)(s_part + ((2 * 2 + 0) * 4 + kg) * 512))[c7] = v0;
    ((float4*)(s_part + ((2 * 2 + 1) * 4 + kg) * 512))[c7] = v1;
    __syncthreads();
    // combine: thread t = output index t (per node, per matrix)
#pragma unroll
    for (int rr = 0; rr < 2; rr++) {
        float q = bq[layer * INNER + t];
        float k = bkv[layer * 2 * INNER + t];
        float v = bkv[layer * 2 * INNER + INNER + t];
#pragma unroll
        for (int g = 0; g < 4; g++) {
            q += s_part[((0 * 2 + rr) * 4 + g) * 512 + t];
            k += s_part[((1 * 2 + rr) * 4 + g) * 512 + t];
            v += s_part[((2 * 2 + rr) * 4 + g) * 512 + t];
        }
        qb[(size_t)(bn0 + rr) * INNER + t] = q;
        kb[(size_t)(bn0 + rr) * INNER + t] = k;
        vb[(size_t)(bn0 + rr) * INNER + t] = v;
    }
}

// ---------- kernels ----------

__global__ __launch_bounds__(512, 2) void k_pre(const int* indices, const float* noise,
                                                const float* atom_emb,
                                                const float* ln1_g, const float* ln1_b,
                                                const float* Wq, const float* bq,
                                                const float* Wkv, const float* bkv,
                                                float* nodes, float* qb, float* kb, float* vb) {
    int bn0 = blockIdx.x * 2;
    int t  = threadIdx.x;
    int d  = t & 127;
    int r  = t >> 7;
    __shared__ float s_xn[256];
    __shared__ float s_red[8];
    __shared__ float s_part[12288];
    float nd = 0.0f;
    if (t < 256) {
        int idx = indices[bn0 + r];
        nd = (d < NF) ? atom_emb[idx * NF + d] : noise[0];
        nodes[(bn0 + r) * DIMM + d] = nd;
    }
    ln_qkv_R2(nd, t, bn0, 0, ln1_g, ln1_b, Wq, bq, Wkv, bkv, qb, kb, vb, s_xn, s_red, s_part);
}

// One block per (b,i) query row. 1024 threads: 8 j-groups x 128 threads.
// Thread owns a head-dim quad; 16 lanes per head -> 4-stage shuffle reduce.
// Softmax without max-tracking (|sim| small).
__global__ __launch_bounds__(1024, 4) void k_attn(int layer, const float* coords, const int* bonds,
                                                  const float* We, const float* be,
                                                  const float* qb, const float* kb, const float* vb,
                                                  float* ao) {
    int bn = blockIdx.x;
    int b = bn >> 7, i = bn & 127;
    int tid = threadIdx.x;
    int jg = tid >> 7;   // 0..7
    int c  = tid & 127;  // quad index, head h = c>>4
    int h  = c >> 4;

    __shared__ float scoord[3 * NN];
    __shared__ float sedge[3 * NN];
    __shared__ int   sadj[NN];
    __shared__ float s_o[8 * INNER];
    __shared__ float s_l[8 * HEADS];

    // issue per-thread global loads early (independent of LDS staging)
    const float4* qR  = (const float4*)(qb + (size_t)bn * INNER);
    const float4* WeR = (const float4*)(We + (size_t)layer * 3 * INNER);
    float4 qv  = qR[c];
    float4 we0 = WeR[c], we1 = WeR[128 + c], we2 = WeR[256 + c];
    float4 bev = ((const float4*)(be + (size_t)layer * INNER))[c];

    if (tid < 3 * NN) scoord[tid] = coords[b * 3 * NN + tid];
    if (tid < NN) sadj[tid] = 0;
    __syncthreads();
    if (tid < EE) {
        int e0 = bonds[2 * tid], e1 = bonds[2 * tid + 1];
        if (e0 == i) sadj[e1] = 1;
        if (e1 == i) sadj[e0] = 1;
    }
    __syncthreads();
    if (tid < NN) {
        int j = tid;
        float msk = sadj[j] ? 1.0f : 0.0f;
        sedge[3 * j + 0] = msk * (scoord[3 * i + 0] - scoord[3 * j + 0]);
        sedge[3 * j + 1] = msk * (scoord[3 * i + 1] - scoord[3 * j + 1]);
        sedge[3 * j + 2] = msk * (scoord[3 * i + 2] - scoord[3 * j + 2]);
    }
    __syncthreads();

    const float4* kR = (const float4*)(kb + (size_t)b * NN * INNER);
    const float4* vR = (const float4*)(vb + (size_t)b * NN * INNER);

    float l_run = 0.0f;
    float4 o_run = {0, 0, 0, 0};
    int j0 = jg * 16;
#pragma unroll 8
    for (int jj = 0; jj < 16; jj++) {
        int j = j0 + jj;
        float ex = sedge[3 * j], ey = sedge[3 * j + 1], ez = sedge[3 * j + 2];
        float4 e;
        e.x = bev.x + ex * we0.x + ey * we1.x + ez * we2.x;
        e.y = bev.y + ex * we0.y + ey * we1.y + ez * we2.y;
        e.z = bev.z + ex * we0.z + ey * we1.z + ez * we2.z;
        e.w = bev.w + ex * we0.w + ey * we1.w + ez * we2.w;
        float4 kv = kR[j * 128 + c];
        float s = (qv.x * (kv.x + e.x) + qv.y * (kv.y + e.y))
                + (qv.z * (kv.z + e.z) + qv.w * (kv.w + e.w));
        s += __shfl_xor(s, 1, 64);
        s += __shfl_xor(s, 2, 64);
        s += __shfl_xor(s, 4, 64);
        s += __shfl_xor(s, 8, 64);
        float p = __expf(s * 0.125f);
        float4 vv = vR[j * 128 + c];
        l_run += p;
        o_run.x += p * (vv.x + e.x);
        o_run.y += p * (vv.y + e.y);
        o_run.z += p * (vv.z + e.z);
        o_run.w += p * (vv.w + e.w);
    }
    ((float4*)(s_o + jg * INNER))[c] = o_run;
    if ((c & 15) == 0) s_l[jg * HEADS + h] = l_run;
    __syncthreads();
    if (jg == 0) {
        float4 o = o_run;
        float l = l_run;
#pragma unroll
        for (int g = 1; g < 8; g++) {
            float4 og = ((float4*)(s_o + g * INNER))[c];
            o.x += og.x; o.y += og.y; o.z += og.z; o.w += og.w;
            l += s_l[g * HEADS + h];
        }
        float inv = 1.0f / l;
        float4 rr; rr.x = o.x * inv; rr.y = o.y * inv; rr.z = o.z * inv; rr.w = o.w * inv;
        ((float4*)(ao + (size_t)bn * INNER))[c] = rr;
    }
}

// Post-attention for 2 nodes per block (bn0, bn0+1), 512 threads.
__global__ __launch_bounds__(512, 2) void k_post(int layer,
                                                 const float* Wo, const float* bo, const float* Wg1,
                                                 const float* ln2_g, const float* ln2_b,
                                                 const float* W1, const float* b1,
                                                 const float* W2, const float* b2,
                                                 const float* Wg2,
                                                 const float* ln1_g, const float* ln1_b,
                                                 const float* Wq, const float* bq,
                                                 const float* Wkv, const float* bkv,
                                                 float* nodes, float* qb, float* kb, float* vb,
                                                 const float* ao) {
    int bn0 = blockIdx.x * 2;
    int t  = threadIdx.x;
    int d  = t & 127;
    int r  = t >> 7;
    bool own = (t < 256);

    __shared__ float s_ao[2 * INNER];
    __shared__ float s_h[2 * INNER];
    __shared__ float s_xn[256];
    __shared__ float s_red[8];
    __shared__ float s_part[12288];

    // stage ao for both nodes (1024 floats = 256 float4, threads 0..255)
    float res = 0.0f;
    if (own) {
        ((float4*)s_ao)[t] = ((const float4*)(ao + (size_t)bn0 * INNER))[t];
        res = nodes[(bn0 + r) * DIMM + d];
    }
    __syncthreads();

    // ---- Wo-proj: 128 outs/node, K=512. c5 = out quad (32), kg16 = K-group (16x32).
    int c5   = t & 31;
    int kg16 = t >> 5;
    {
        const float4* WoR = (const float4*)(Wo + (size_t)layer * INNER * DIMM);
        float4 a0 = {0,0,0,0}, a1 = {0,0,0,0};
        int kkb = kg16 * 32;
#pragma unroll 8
        for (int rr = 0; rr < 32; rr++) {
            int kk = kkb + rr;
            float4 w = WoR[kk * 32 + c5];
            fma4(a0, s_ao[kk], w);
            fma4(a1, s_ao[512 + kk], w);
        }
        ((float4*)(s_part + (0 * 16 + kg16) * 128))[c5] = a0;
        ((float4*)(s_part + (2 * 16 + kg16) * 128))[c5] = a1;  // node1 region offset 2*16*128
    }
    __syncthreads();
    float x = 0.0f;
    if (own) {
        x = bo[layer * DIMM + d];
#pragma unroll
        for (int g = 0; g < 16; g++) x += s_part[(r * 32 + g) * 128 + d];
    }

    // ---- gated residual 1 (per node)
    const float* Wg1_l = Wg1 + layer * 3 * DIMM;
    float texpr = own ? (x * Wg1_l[d] + res * Wg1_l[DIMM + d] + (x - res) * Wg1_l[2 * DIMM + d]) : 0.0f;
    float g1 = group_reduce_128(texpr, s_red);
    g1 = 1.0f / (1.0f + __expf(-g1));
    float n1 = x * g1 + res * (1.0f - g1);

    // ---- LN2
    float m   = group_reduce_128(own ? n1 : 0.0f, s_red) * (1.0f / 128.0f);
    float df  = n1 - m;
    float var = group_reduce_128(own ? df * df : 0.0f, s_red) * (1.0f / 128.0f);
    float xn  = df * rsqrtf(var + 1e-5f) * ln2_g[layer * DIMM + d] + ln2_b[layer * DIMM + d];
    if (own) s_xn[r * 128 + d] = xn;
    __syncthreads();

    // ---- FF1 + gelu: 512 outs/node, K=128. c7 = out quad (128), kg4 = K-group (4x32).
    int c7  = t & 127;
    int kg4 = t >> 7;
    {
        const float4* W1R = (const float4*)(W1 + (size_t)layer * DIMM * 4 * DIMM);
        float4 a0 = {0,0,0,0}, a1 = {0,0,0,0};
        int kkb = kg4 * 32;
#pragma unroll 8
        for (int rr = 0; rr < 32; rr++) {
            int kk = kkb + rr;
            float4 w = W1R[kk * 128 + c7];
            fma4(a0, s_xn[kk], w);
            fma4(a1, s_xn[128 + kk], w);
        }
        ((float4*)(s_part + (0 * 4 + kg4) * 512))[c7] = a0;
        ((float4*)(s_part + (2 * 4 + kg4) * 512))[c7] = a1;  // node1 region offset 2*4*512
    }
    __syncthreads();
#pragma unroll
    for (int rr = 0; rr < 2; rr++) {
        float a = b1[layer * 4 * DIMM + t];
#pragma unroll
        for (int g = 0; g < 4; g++) a += s_part[((rr * 2 + 0) * 4 + g) * 512 + t];
        a = 0.5f * a * (1.0f + erff(a * 0.70710678f));
        s_h[rr * 512 + t] = a;
    }
    __syncthreads();

    // ---- FF2: 128 outs/node, K=512 (same shape as Wo)
    {
        const float4* W2R = (const float4*)(W2 + (size_t)layer * 4 * DIMM * DIMM);
        float4 a0 = {0,0,0,0}, a1 = {0,0,0,0};
        int kkb = kg16 * 32;
#pragma unroll 8
        for (int rr = 0; rr < 32; rr++) {
            int kk = kkb + rr;
            float4 w = W2R[kk * 32 + c5];
            fma4(a0, s_h[kk], w);
            fma4(a1, s_h[512 + kk], w);
        }
        ((float4*)(s_part + (0 * 16 + kg16) * 128))[c5] = a0;
        ((float4*)(s_part + (2 * 16 + kg16) * 128))[c5] = a1;
    }
    __syncthreads();
    float y = 0.0f;
    if (own) {
        y = b2[layer * DIMM + d];
#pragma unroll
        for (int g = 0; g < 16; g++) y += s_part[(r * 32 + g) * 128 + d];
    }

    // ---- gated residual 2
    const float* Wg2_l = Wg2 + layer * 3 * DIMM;
    texpr = own ? (y * Wg2_l[d] + n1 * Wg2_l[DIMM + d] + (y - n1) * Wg2_l[2 * DIMM + d]) : 0.0f;
    float g2 = group_reduce_128(texpr, s_red);
    g2 = 1.0f / (1.0f + __expf(-g2));
    float n2 = y * g2 + n1 * (1.0f - g2);
    if (own) nodes[(bn0 + r) * DIMM + d] = n2;

    if (layer < DEPTH - 1) {
        ln_qkv_R2(own ? n2 : 0.0f, t, bn0, layer + 1, ln1_g, ln1_b, Wq, bq, Wkv, bkv,
                  qb, kb, vb, s_xn, s_red, s_part);
    }
}

// Final: sum over nodes of (nodes @ Wlin + blin) -> scalar.
__global__ __launch_bounds__(256) void k_final(const float* nodes, const float* Wlin,
                                               const float* blin, float* out) {
    int t = threadIdx.x; // node index
    __shared__ float s_w[DIMM];
    if (t < DIMM) s_w[t] = Wlin[t];
    __syncthreads();
    float s = blin[0];
    const float4* nr = (const float4*)(nodes + t * DIMM);
#pragma unroll 8
    for (int q = 0; q < 32; q++) {
        float4 n = nr[q];
        s += n.x * s_w[4 * q] + n.y * s_w[4 * q + 1] + n.z * s_w[4 * q + 2] + n.w * s_w[4 * q + 3];
    }
#pragma unroll
    for (int off = 32; off > 0; off >>= 1) s += __shfl_xor(s, off, 64);
    __shared__ float sb[4];
    int wave = t >> 6, lane = t & 63;
    if (lane == 0) sb[wave] = s;
    __syncthreads();
    if (t == 0) out[0] = sb[0] + sb[1] + sb[2] + sb[3];
}

extern "C" void kernel_launch(void* const* d_in, const int* in_sizes, int n_in,
                              void* d_out, int out_size, void* d_ws, size_t ws_size,
                              hipStream_t stream) {
    const int*   indices = (const int*)d_in[0];
    const float* coords  = (const float*)d_in[1];
    const int*   bonds   = (const int*)d_in[2];
    const float* noise   = (const float*)d_in[3];
    const float* atom_emb= (const float*)d_in[4];
    const float* ln1_g   = (const float*)d_in[5];
    const float* ln1_b   = (const float*)d_in[6];
    const float* Wq      = (const float*)d_in[7];
    const float* bq      = (const float*)d_in[8];
    const float* Wkv     = (const float*)d_in[9];
    const float* bkv     = (const float*)d_in[10];
    const float* We      = (const float*)d_in[11];
    const float* be      = (const float*)d_in[12];
    const float* Wo      = (const float*)d_in[13];
    const float* bo      = (const float*)d_in[14];
    const float* Wg1     = (const float*)d_in[15];
    const float* ln2_g   = (const float*)d_in[16];
    const float* ln2_b   = (const float*)d_in[17];
    const float* W1      = (const float*)d_in[18];
    const float* b1      = (const float*)d_in[19];
    const float* W2      = (const float*)d_in[20];
    const float* b2      = (const float*)d_in[21];
    const float* Wg2     = (const float*)d_in[22];
    const float* Wlin    = (const float*)d_in[23];
    const float* blin    = (const float*)d_in[24];

    float* ws    = (float*)d_ws;
    float* nodes = ws;                               // B*N*DIM   = 32768
    float* qb    = nodes + BB * NN * DIMM;           // B*N*INNER = 131072
    float* kb    = qb + BB * NN * INNER;
    float* vb    = kb + BB * NN * INNER;
    float* ao    = vb + BB * NN * INNER;

    k_pre<<<BB * NN / 2, 512, 0, stream>>>(indices, noise, atom_emb, ln1_g, ln1_b,
                                           Wq, bq, Wkv, bkv, nodes, qb, kb, vb);
    for (int l = 0; l < DEPTH; l++) {
        k_attn<<<BB * NN, 1024, 0, stream>>>(l, coords, bonds, We, be, qb, kb, vb, ao);
        k_post<<<BB * NN / 2, 512, 0, stream>>>(l, Wo, bo, Wg1, ln2_g, ln2_b, W1, b1, W2, b2,
                                                Wg2, ln1_g, ln1_b, Wq, bq, Wkv, bkv,
                                                nodes, qb, kb, vb, ao);
    }
    k_final<<<1, 256, 0, stream>>>(nodes, Wlin, blin, (float*)d_out);
}

// Round 5
// 329.744 us; speedup vs baseline: 1.1329x; 1.1329x over previous
//
#include <hip/hip_runtime.h>
#include <math.h>

#define DEPTH 6
#define HEADS 8
#define BB    2
#define NN    128
#define EE    160
#define NF    127
#define DIMM  128
#define INNER 512

#define KV_SLAB (BB * NN * INNER)   // floats per k/v slab

__device__ __forceinline__ void fma4(float4& acc, float a, const float4 w) {
    acc.x += a * w.x; acc.y += a * w.y; acc.z += a * w.z; acc.w += a * w.w;
}

// 512-thread (8-wave) block sum; result broadcast.
__device__ __forceinline__ float block_reduce_sum_8w(float val, float* sbuf) {
#pragma unroll
    for (int off = 32; off > 0; off >>= 1) val += __shfl_xor(val, off, 64);
    int wave = threadIdx.x >> 6;
    if ((threadIdx.x & 63) == 0) sbuf[wave] = val;
    __syncthreads();
    float r = sbuf[0] + sbuf[1] + sbuf[2] + sbuf[3] + sbuf[4] + sbuf[5] + sbuf[6] + sbuf[7];
    __syncthreads();
    return r;
}

// LN over 128 dims + QKV projection for node bn. 512 threads, explicit
// register-prefetch (8-deep, 3 streams = 24 float4 in flight per round).
// s_xn: 128 f, s_red: 8 f, s_part: 6144 f.
__device__ void ln_qkv_pf(float nd, bool own, int t, int bn, int layer,
                          const float* ln_g, const float* ln_b,
                          const float* Wq, const float* bq,
                          const float* Wkv, const float* bkv,
                          float* qout, float* kout, float* vout,
                          float* s_xn, float* s_red, float* s_part) {
    int d = t & 127;
    float m   = block_reduce_sum_8w(own ? nd : 0.0f, s_red) * (1.0f / 128.0f);
    float df  = nd - m;
    float var = block_reduce_sum_8w(own ? df * df : 0.0f, s_red) * (1.0f / 128.0f);
    float xn  = df * rsqrtf(var + 1e-5f) * ln_g[layer * DIMM + d] + ln_b[layer * DIMM + d];
    if (own) s_xn[d] = xn;
    __syncthreads();

    int c7  = t & 127;   // output quad within each 512-wide matrix
    int kg  = t >> 7;    // 4 K-groups of 32
    int kkb = kg * 32;
    const float4* WqR  = (const float4*)(Wq  + (size_t)layer * DIMM * INNER);
    const float4* WkvR = (const float4*)(Wkv + (size_t)layer * DIMM * 2 * INNER);
    float4 aq = {0,0,0,0}, ak = {0,0,0,0}, av = {0,0,0,0};
#pragma unroll
    for (int base = 0; base < 32; base += 8) {
        float4 wq[8], wk[8], wv[8];
#pragma unroll
        for (int p = 0; p < 8; p++) {
            int kk = kkb + base + p;
            wq[p] = WqR[kk * 128 + c7];
            wk[p] = WkvR[kk * 256 + c7];
            wv[p] = WkvR[kk * 256 + 128 + c7];
        }
#pragma unroll
        for (int p = 0; p < 8; p++) {
            float a = s_xn[kkb + base + p];
            fma4(aq, a, wq[p]); fma4(ak, a, wk[p]); fma4(av, a, wv[p]);
        }
    }
    ((float4*)(s_part + (0 * 4 + kg) * 512))[c7] = aq;
    ((float4*)(s_part + (1 * 4 + kg) * 512))[c7] = ak;
    ((float4*)(s_part + (2 * 4 + kg) * 512))[c7] = av;
    __syncthreads();
    float q = bq[layer * INNER + t];
    float k = bkv[layer * 2 * INNER + t];
    float v = bkv[layer * 2 * INNER + INNER + t];
#pragma unroll
    for (int g = 0; g < 4; g++) {
        q += s_part[(0 * 4 + g) * 512 + t];
        k += s_part[(1 * 4 + g) * 512 + t];
        v += s_part[(2 * 4 + g) * 512 + t];
    }
    qout[(size_t)bn * INNER + t] = q;
    kout[(size_t)bn * INNER + t] = k;
    vout[(size_t)bn * INNER + t] = v;
}

// ---------- kernels ----------

__global__ __launch_bounds__(512, 2) void k_pre(const int* indices, const float* noise,
                                                const float* atom_emb,
                                                const float* ln1_g, const float* ln1_b,
                                                const float* Wq, const float* bq,
                                                const float* Wkv, const float* bkv,
                                                float* nodes, float* qb, float* kb, float* vb) {
    int bn = blockIdx.x;
    int t  = threadIdx.x;
    int d  = t & 127;
    bool own = (t < 128);
    __shared__ float s_xn[128];
    __shared__ float s_red[8];
    __shared__ float s_part[6144];
    float nd = 0.0f;
    if (own) {
        int idx = indices[bn];
        nd = (d < NF) ? atom_emb[idx * NF + d] : noise[0];
        nodes[bn * DIMM + d] = nd;
    }
    ln_qkv_pf(nd, own, t, bn, 0, ln1_g, ln1_b, Wq, bq, Wkv, bkv, qb, kb, vb,
              s_xn, s_red, s_part);
}

// Fused per-layer kernel: block bn does attention for node bn (online softmax,
// no max-tracking; |sim| is small), then the full post pipeline for node bn,
// then LN1+QKV for the next layer. k/v double-buffered by layer parity.
__global__ __launch_bounds__(512, 2) void k_layer(int layer,
        const float* coords, const int* bonds,
        const float* We, const float* be,
        float* qb, const float* kin, const float* vin,
        float* kout, float* vout,
        const float* Wo, const float* bo, const float* Wg1,
        const float* ln2_g, const float* ln2_b,
        const float* W1, const float* b1,
        const float* W2, const float* b2,
        const float* Wg2,
        const float* ln1_g, const float* ln1_b,
        const float* Wq, const float* bq,
        const float* Wkv, const float* bkv,
        float* nodes) {
    int bn = blockIdx.x;
    int b = bn >> 7, i = bn & 127;
    int t = threadIdx.x;
    int d = t & 127;
    bool own = (t < 128);

    __shared__ float scoord[3 * NN];
    __shared__ float sedge[3 * NN];
    __shared__ int   sadj[NN];
    __shared__ float s_o[4 * INNER];     // 4 j-group partials
    __shared__ float s_l[4 * HEADS];
    __shared__ float s_ao[INNER];
    __shared__ float s_h[INNER];
    __shared__ float s_xn[128];
    __shared__ float s_red[8];
    __shared__ float s_part[6144];

    // ---------- Phase A: attention ----------
    int jg = t >> 7;     // 0..3, each handles 32 j's
    int c  = t & 127;    // head-dim quad; head h = c>>4
    int h  = c >> 4;

    const float4* qR  = (const float4*)(qb + (size_t)bn * INNER);
    const float4* WeR = (const float4*)(We + (size_t)layer * 3 * INNER);
    float4 qv  = qR[c];
    float4 we0 = WeR[c], we1 = WeR[128 + c], we2 = WeR[256 + c];
    float4 bev = ((const float4*)(be + (size_t)layer * INNER))[c];
    float res = own ? nodes[bn * DIMM + d] : 0.0f;

    if (t < 3 * NN) scoord[t] = coords[b * 3 * NN + t];
    if (t < NN) sadj[t] = 0;
    __syncthreads();
    if (t < EE) {
        int e0 = bonds[2 * t], e1 = bonds[2 * t + 1];
        if (e0 == i) sadj[e1] = 1;
        if (e1 == i) sadj[e0] = 1;
    }
    __syncthreads();
    if (t < NN) {
        int j = t;
        float msk = sadj[j] ? 1.0f : 0.0f;
        sedge[3 * j + 0] = msk * (scoord[3 * i + 0] - scoord[3 * j + 0]);
        sedge[3 * j + 1] = msk * (scoord[3 * i + 1] - scoord[3 * j + 1]);
        sedge[3 * j + 2] = msk * (scoord[3 * i + 2] - scoord[3 * j + 2]);
    }
    __syncthreads();

    const float4* kR = (const float4*)(kin + (size_t)b * NN * INNER);
    const float4* vR = (const float4*)(vin + (size_t)b * NN * INNER);

    float l_run = 0.0f;
    float4 o_run = {0, 0, 0, 0};
    int j0 = jg * 32;
#pragma unroll
    for (int base = 0; base < 32; base += 8) {
        float4 kvv[8], vvv[8];
#pragma unroll
        for (int p = 0; p < 8; p++) {
            int j = j0 + base + p;
            kvv[p] = kR[j * 128 + c];
            vvv[p] = vR[j * 128 + c];
        }
#pragma unroll
        for (int p = 0; p < 8; p++) {
            int j = j0 + base + p;
            float ex = sedge[3 * j], ey = sedge[3 * j + 1], ez = sedge[3 * j + 2];
            float4 e;
            e.x = bev.x + ex * we0.x + ey * we1.x + ez * we2.x;
            e.y = bev.y + ex * we0.y + ey * we1.y + ez * we2.y;
            e.z = bev.z + ex * we0.z + ey * we1.z + ez * we2.z;
            e.w = bev.w + ex * we0.w + ey * we1.w + ez * we2.w;
            float4 kv = kvv[p];
            float s = (qv.x * (kv.x + e.x) + qv.y * (kv.y + e.y))
                    + (qv.z * (kv.z + e.z) + qv.w * (kv.w + e.w));
            s += __shfl_xor(s, 1, 64);
            s += __shfl_xor(s, 2, 64);
            s += __shfl_xor(s, 4, 64);
            s += __shfl_xor(s, 8, 64);
            float pp = __expf(s * 0.125f);
            float4 vv = vvv[p];
            l_run += pp;
            o_run.x += pp * (vv.x + e.x);
            o_run.y += pp * (vv.y + e.y);
            o_run.z += pp * (vv.z + e.z);
            o_run.w += pp * (vv.w + e.w);
        }
    }
    ((float4*)(s_o + jg * INNER))[c] = o_run;
    if ((c & 15) == 0) s_l[jg * HEADS + h] = l_run;
    __syncthreads();
    if (jg == 0) {
        float4 o = o_run;
        float l = l_run;
#pragma unroll
        for (int g = 1; g < 4; g++) {
            float4 og = ((float4*)(s_o + g * INNER))[c];
            o.x += og.x; o.y += og.y; o.z += og.z; o.w += og.w;
            l += s_l[g * HEADS + h];
        }
        float inv = 1.0f / l;
        float4 rr; rr.x = o.x * inv; rr.y = o.y * inv; rr.z = o.z * inv; rr.w = o.w * inv;
        ((float4*)s_ao)[c] = rr;
    }
    __syncthreads();

    // ---------- Phase B: post pipeline ----------
    // Wo-proj: 128 outs, K=512. c5 = out quad (32), kg16 = K-group (16x32).
    int c5   = t & 31;
    int kg16 = t >> 5;
    {
        const float4* WoR = (const float4*)(Wo + (size_t)layer * INNER * DIMM);
        int kkb = kg16 * 32;
        float4 acc = {0, 0, 0, 0};
#pragma unroll
        for (int half = 0; half < 2; half++) {
            float4 w[16];
#pragma unroll
            for (int p = 0; p < 16; p++) w[p] = WoR[(kkb + half * 16 + p) * 32 + c5];
#pragma unroll
            for (int p = 0; p < 16; p++) fma4(acc, s_ao[kkb + half * 16 + p], w[p]);
        }
        ((float4*)(s_part + kg16 * 128))[c5] = acc;
    }
    __syncthreads();
    float x = 0.0f;
    if (own) {
        x = bo[layer * DIMM + d];
#pragma unroll
        for (int g = 0; g < 16; g++) x += s_part[g * 128 + d];
    }

    // gated residual 1
    const float* Wg1_l = Wg1 + layer * 3 * DIMM;
    float texpr = own ? (x * Wg1_l[d] + res * Wg1_l[DIMM + d] + (x - res) * Wg1_l[2 * DIMM + d]) : 0.0f;
    float g1 = block_reduce_sum_8w(texpr, s_red);
    g1 = 1.0f / (1.0f + __expf(-g1));
    float n1 = x * g1 + res * (1.0f - g1);

    // LN2
    float m   = block_reduce_sum_8w(own ? n1 : 0.0f, s_red) * (1.0f / 128.0f);
    float df  = n1 - m;
    float var = block_reduce_sum_8w(own ? df * df : 0.0f, s_red) * (1.0f / 128.0f);
    float xn  = df * rsqrtf(var + 1e-5f) * ln2_g[layer * DIMM + d] + ln2_b[layer * DIMM + d];
    if (own) s_xn[d] = xn;
    __syncthreads();

    // FF1 + exact gelu: 512 outs, K=128. c7 = out quad (128), kg4 = K-group (4x32).
    int c7  = t & 127;
    int kg4 = t >> 7;
    {
        const float4* W1R = (const float4*)(W1 + (size_t)layer * DIMM * 4 * DIMM);
        int kkb = kg4 * 32;
        float4 acc = {0, 0, 0, 0};
#pragma unroll
        for (int half = 0; half < 2; half++) {
            float4 w[16];
#pragma unroll
            for (int p = 0; p < 16; p++) w[p] = W1R[(kkb + half * 16 + p) * 128 + c7];
#pragma unroll
            for (int p = 0; p < 16; p++) fma4(acc, s_xn[kkb + half * 16 + p], w[p]);
        }
        ((float4*)(s_part + kg4 * 512))[c7] = acc;
    }
    __syncthreads();
    {
        float a = b1[layer * 4 * DIMM + t];
#pragma unroll
        for (int g = 0; g < 4; g++) a += s_part[g * 512 + t];
        a = 0.5f * a * (1.0f + erff(a * 0.70710678f));
        s_h[t] = a;
    }
    __syncthreads();

    // FF2: 128 outs, K=512
    {
        const float4* W2R = (const float4*)(W2 + (size_t)layer * 4 * DIMM * DIMM);
        int kkb = kg16 * 32;
        float4 acc = {0, 0, 0, 0};
#pragma unroll
        for (int half = 0; half < 2; half++) {
            float4 w[16];
#pragma unroll
            for (int p = 0; p < 16; p++) w[p] = W2R[(kkb + half * 16 + p) * 32 + c5];
#pragma unroll
            for (int p = 0; p < 16; p++) fma4(acc, s_h[kkb + half * 16 + p], w[p]);
        }
        ((float4*)(s_part + kg16 * 128))[c5] = acc;
    }
    __syncthreads();
    float y = 0.0f;
    if (own) {
        y = b2[layer * DIMM + d];
#pragma unroll
        for (int g = 0; g < 16; g++) y += s_part[g * 128 + d];
    }

    // gated residual 2
    const float* Wg2_l = Wg2 + layer * 3 * DIMM;
    texpr = own ? (y * Wg2_l[d] + n1 * Wg2_l[DIMM + d] + (y - n1) * Wg2_l[2 * DIMM + d]) : 0.0f;
    float g2 = block_reduce_sum_8w(texpr, s_red);
    g2 = 1.0f / (1.0f + __expf(-g2));
    float n2 = y * g2 + n1 * (1.0f - g2);
    if (own) nodes[bn * DIMM + d] = n2;

    if (layer < DEPTH - 1) {
        ln_qkv_pf(own ? n2 : 0.0f, own, t, bn, layer + 1, ln1_g, ln1_b, Wq, bq, Wkv, bkv,
                  qb, kout, vout, s_xn, s_red, s_part);
    }
}

// Final: sum over nodes of (nodes @ Wlin + blin) -> scalar.
__global__ __launch_bounds__(256) void k_final(const float* nodes, const float* Wlin,
                                               const float* blin, float* out) {
    int t = threadIdx.x; // node index
    __shared__ float s_w[DIMM];
    if (t < DIMM) s_w[t] = Wlin[t];
    __syncthreads();
    float s = blin[0];
    const float4* nr = (const float4*)(nodes + t * DIMM);
#pragma unroll 8
    for (int q = 0; q < 32; q++) {
        float4 n = nr[q];
        s += n.x * s_w[4 * q] + n.y * s_w[4 * q + 1] + n.z * s_w[4 * q + 2] + n.w * s_w[4 * q + 3];
    }
#pragma unroll
    for (int off = 32; off > 0; off >>= 1) s += __shfl_xor(s, off, 64);
    __shared__ float sb[4];
    int wave = t >> 6, lane = t & 63;
    if (lane == 0) sb[wave] = s;
    __syncthreads();
    if (t == 0) out[0] = sb[0] + sb[1] + sb[2] + sb[3];
}

extern "C" void kernel_launch(void* const* d_in, const int* in_sizes, int n_in,
                              void* d_out, int out_size, void* d_ws, size_t ws_size,
                              hipStream_t stream) {
    const int*   indices = (const int*)d_in[0];
    const float* coords  = (const float*)d_in[1];
    const int*   bonds   = (const int*)d_in[2];
    const float* noise   = (const float*)d_in[3];
    const float* atom_emb= (const float*)d_in[4];
    const float* ln1_g   = (const float*)d_in[5];
    const float* ln1_b   = (const float*)d_in[6];
    const float* Wq      = (const float*)d_in[7];
    const float* bq      = (const float*)d_in[8];
    const float* Wkv     = (const float*)d_in[9];
    const float* bkv     = (const float*)d_in[10];
    const float* We      = (const float*)d_in[11];
    const float* be      = (const float*)d_in[12];
    const float* Wo      = (const float*)d_in[13];
    const float* bo      = (const float*)d_in[14];
    const float* Wg1     = (const float*)d_in[15];
    const float* ln2_g   = (const float*)d_in[16];
    const float* ln2_b   = (const float*)d_in[17];
    const float* W1      = (const float*)d_in[18];
    const float* b1      = (const float*)d_in[19];
    const float* W2      = (const float*)d_in[20];
    const float* b2      = (const float*)d_in[21];
    const float* Wg2     = (const float*)d_in[22];
    const float* Wlin    = (const float*)d_in[23];
    const float* blin    = (const float*)d_in[24];

    float* ws    = (float*)d_ws;
    float* nodes = ws;                       // 32768 floats
    float* qb    = nodes + BB * NN * DIMM;   // 131072 floats
    float* kb    = qb + KV_SLAB;             // 2 slabs
    float* vb    = kb + 2 * KV_SLAB;         // 2 slabs

    k_pre<<<BB * NN, 512, 0, stream>>>(indices, noise, atom_emb, ln1_g, ln1_b,
                                       Wq, bq, Wkv, bkv, nodes, qb, kb, vb);
    for (int l = 0; l < DEPTH; l++) {
        const float* kin = kb + (size_t)(l & 1) * KV_SLAB;
        const float* vin = vb + (size_t)(l & 1) * KV_SLAB;
        float* kout = kb + (size_t)((l + 1) & 1) * KV_SLAB;
        float* vout = vb + (size_t)((l + 1) & 1) * KV_SLAB;
        k_layer<<<BB * NN, 512, 0, stream>>>(l, coords, bonds, We, be,
                                             qb, kin, vin, kout, vout,
                                             Wo, bo, Wg1, ln2_g, ln2_b, W1, b1, W2, b2,
                                             Wg2, ln1_g, ln1_b, Wq, bq, Wkv, bkv, nodes);
    }
    k_final<<<1, 256, 0, stream>>>(nodes, Wlin, blin, (float*)d_out);
}

// Round 6
// 326.781 us; speedup vs baseline: 1.1432x; 1.0091x over previous
//
#include <hip/hip_runtime.h>
#include <math.h>

#define DEPTH 6
#define HEADS 8
#define BB    2
#define NN    128
#define EE    160
#define NF    127
#define DIMM  128
#define INNER 512

#define KV_SLAB (BB * NN * INNER)   // floats per k/v slab

__device__ __forceinline__ void fma4(float4& acc, float a, const float4 w) {
    acc.x += a * w.x; acc.y += a * w.y; acc.z += a * w.z; acc.w += a * w.w;
}

// 512-thread (8-wave) block sum; result broadcast.
__device__ __forceinline__ float block_reduce_sum_8w(float val, float* sbuf) {
#pragma unroll
    for (int off = 32; off > 0; off >>= 1) val += __shfl_xor(val, off, 64);
    int wave = threadIdx.x >> 6;
    if ((threadIdx.x & 63) == 0) sbuf[wave] = val;
    __syncthreads();
    float r = sbuf[0] + sbuf[1] + sbuf[2] + sbuf[3] + sbuf[4] + sbuf[5] + sbuf[6] + sbuf[7];
    __syncthreads();
    return r;
}

// LN over 128 dims + QKV projection for node bn. 512 threads, explicit
// register-prefetch (8-deep x 3 streams = 24 float4 in flight).
__device__ void ln_qkv_pf(float nd, bool own, int t, int bn, int layer,
                          const float* ln_g, const float* ln_b,
                          const float* Wq, const float* bq,
                          const float* Wkv, const float* bkv,
                          float* qout, float* kout, float* vout,
                          float* s_xn, float* s_red, float* s_part) {
    int d = t & 127;
    float m   = block_reduce_sum_8w(own ? nd : 0.0f, s_red) * (1.0f / 128.0f);
    float df  = nd - m;
    float var = block_reduce_sum_8w(own ? df * df : 0.0f, s_red) * (1.0f / 128.0f);
    float xn  = df * rsqrtf(var + 1e-5f) * ln_g[layer * DIMM + d] + ln_b[layer * DIMM + d];
    if (own) s_xn[d] = xn;
    __syncthreads();

    int c7  = t & 127;   // output quad within each 512-wide matrix
    int kg  = t >> 7;    // 4 K-groups of 32
    int kkb = kg * 32;
    const float4* WqR  = (const float4*)(Wq  + (size_t)layer * DIMM * INNER);
    const float4* WkvR = (const float4*)(Wkv + (size_t)layer * DIMM * 2 * INNER);
    float4 aq = {0,0,0,0}, ak = {0,0,0,0}, av = {0,0,0,0};
#pragma unroll
    for (int base = 0; base < 32; base += 8) {
        float4 wq[8], wk[8], wv[8];
#pragma unroll
        for (int p = 0; p < 8; p++) {
            int kk = kkb + base + p;
            wq[p] = WqR[kk * 128 + c7];
            wk[p] = WkvR[kk * 256 + c7];
            wv[p] = WkvR[kk * 256 + 128 + c7];
        }
#pragma unroll
        for (int p = 0; p < 8; p++) {
            float a = s_xn[kkb + base + p];
            fma4(aq, a, wq[p]); fma4(ak, a, wk[p]); fma4(av, a, wv[p]);
        }
    }
    ((float4*)(s_part + (0 * 4 + kg) * 512))[c7] = aq;
    ((float4*)(s_part + (1 * 4 + kg) * 512))[c7] = ak;
    ((float4*)(s_part + (2 * 4 + kg) * 512))[c7] = av;
    __syncthreads();
    float q = bq[layer * INNER + t];
    float k = bkv[layer * 2 * INNER + t];
    float v = bkv[layer * 2 * INNER + INNER + t];
#pragma unroll
    for (int g = 0; g < 4; g++) {
        q += s_part[(0 * 4 + g) * 512 + t];
        k += s_part[(1 * 4 + g) * 512 + t];
        v += s_part[(2 * 4 + g) * 512 + t];
    }
    qout[(size_t)bn * INNER + t] = q;
    kout[(size_t)bn * INNER + t] = k;
    vout[(size_t)bn * INNER + t] = v;
}

// ---------- kernels ----------

__global__ __launch_bounds__(512)
__attribute__((amdgpu_waves_per_eu(2, 2)))
void k_pre(const int* indices, const float* noise,
           const float* atom_emb,
           const float* ln1_g, const float* ln1_b,
           const float* Wq, const float* bq,
           const float* Wkv, const float* bkv,
           float* nodes, float* qb, float* kb, float* vb) {
    int bn = blockIdx.x;
    int t  = threadIdx.x;
    int d  = t & 127;
    bool own = (t < 128);
    __shared__ float s_xn[128];
    __shared__ float s_red[8];
    __shared__ float s_part[6144];
    float nd = 0.0f;
    if (own) {
        int idx = indices[bn];
        nd = (d < NF) ? atom_emb[idx * NF + d] : noise[0];
        nodes[bn * DIMM + d] = nd;
    }
    ln_qkv_pf(nd, own, t, bn, 0, ln1_g, ln1_b, Wq, bq, Wkv, bkv, qb, kb, vb,
              s_xn, s_red, s_part);
}

// Fused per-layer kernel: attention for node bn + full post pipeline +
// LN1/QKV for next layer. k/v double-buffered by layer parity.
__global__ __launch_bounds__(512)
__attribute__((amdgpu_waves_per_eu(2, 2)))
void k_layer(int layer,
        const float* coords, const int* bonds,
        const float* We, const float* be,
        float* qb, const float* kin, const float* vin,
        float* kout, float* vout,
        const float* Wo, const float* bo, const float* Wg1,
        const float* ln2_g, const float* ln2_b,
        const float* W1, const float* b1,
        const float* W2, const float* b2,
        const float* Wg2,
        const float* ln1_g, const float* ln1_b,
        const float* Wq, const float* bq,
        const float* Wkv, const float* bkv,
        float* nodes) {
    int bn = blockIdx.x;
    int b = bn >> 7, i = bn & 127;
    int t = threadIdx.x;
    int d = t & 127;
    bool own = (t < 128);

    __shared__ float scoord[3 * NN];
    __shared__ float sedge[3 * NN];
    __shared__ int   sadj[NN];
    __shared__ float s_o[4 * INNER];     // 4 j-group partials
    __shared__ float s_l[4 * HEADS];
    __shared__ float s_ao[INNER];
    __shared__ float s_h[INNER];
    __shared__ float s_xn[128];
    __shared__ float s_red[8];
    __shared__ float s_part[6144];

    // ---------- Phase A: attention ----------
    int jg = t >> 7;     // 0..3, each handles 32 j's
    int c  = t & 127;    // head-dim quad; head h = c>>4
    int h  = c >> 4;

    const float4* qR  = (const float4*)(qb + (size_t)bn * INNER);
    const float4* WeR = (const float4*)(We + (size_t)layer * 3 * INNER);
    float4 qv  = qR[c];
    float4 we0 = WeR[c], we1 = WeR[128 + c], we2 = WeR[256 + c];
    float4 bev = ((const float4*)(be + (size_t)layer * INNER))[c];
    float res = own ? nodes[bn * DIMM + d] : 0.0f;

    if (t < 3 * NN) scoord[t] = coords[b * 3 * NN + t];
    if (t < NN) sadj[t] = 0;
    __syncthreads();
    if (t < EE) {
        int e0 = bonds[2 * t], e1 = bonds[2 * t + 1];
        if (e0 == i) sadj[e1] = 1;
        if (e1 == i) sadj[e0] = 1;
    }
    __syncthreads();
    if (t < NN) {
        int j = t;
        float msk = sadj[j] ? 1.0f : 0.0f;
        sedge[3 * j + 0] = msk * (scoord[3 * i + 0] - scoord[3 * j + 0]);
        sedge[3 * j + 1] = msk * (scoord[3 * i + 1] - scoord[3 * j + 1]);
        sedge[3 * j + 2] = msk * (scoord[3 * i + 2] - scoord[3 * j + 2]);
    }
    __syncthreads();

    const float4* kR = (const float4*)(kin + (size_t)b * NN * INNER);
    const float4* vR = (const float4*)(vin + (size_t)b * NN * INNER);

    float l_run = 0.0f;
    float4 o_run = {0, 0, 0, 0};
    int j0 = jg * 32;
#pragma unroll
    for (int base = 0; base < 32; base += 16) {
        float4 kvv[16], vvv[16];
#pragma unroll
        for (int p = 0; p < 16; p++) {
            int j = j0 + base + p;
            kvv[p] = kR[j * 128 + c];
            vvv[p] = vR[j * 128 + c];
        }
#pragma unroll
        for (int p = 0; p < 16; p++) {
            int j = j0 + base + p;
            float ex = sedge[3 * j], ey = sedge[3 * j + 1], ez = sedge[3 * j + 2];
            float4 e;
            e.x = bev.x + ex * we0.x + ey * we1.x + ez * we2.x;
            e.y = bev.y + ex * we0.y + ey * we1.y + ez * we2.y;
            e.z = bev.z + ex * we0.z + ey * we1.z + ez * we2.z;
            e.w = bev.w + ex * we0.w + ey * we1.w + ez * we2.w;
            float4 kv = kvv[p];
            float s = (qv.x * (kv.x + e.x) + qv.y * (kv.y + e.y))
                    + (qv.z * (kv.z + e.z) + qv.w * (kv.w + e.w));
            s += __shfl_xor(s, 1, 64);
            s += __shfl_xor(s, 2, 64);
            s += __shfl_xor(s, 4, 64);
            s += __shfl_xor(s, 8, 64);
            float pp = __expf(s * 0.125f);
            float4 vv = vvv[p];
            l_run += pp;
            o_run.x += pp * (vv.x + e.x);
            o_run.y += pp * (vv.y + e.y);
            o_run.z += pp * (vv.z + e.z);
            o_run.w += pp * (vv.w + e.w);
        }
    }
    ((float4*)(s_o + jg * INNER))[c] = o_run;
    if ((c & 15) == 0) s_l[jg * HEADS + h] = l_run;
    __syncthreads();
    if (jg == 0) {
        float4 o = o_run;
        float l = l_run;
#pragma unroll
        for (int g = 1; g < 4; g++) {
            float4 og = ((float4*)(s_o + g * INNER))[c];
            o.x += og.x; o.y += og.y; o.z += og.z; o.w += og.w;
            l += s_l[g * HEADS + h];
        }
        float inv = 1.0f / l;
        float4 rr; rr.x = o.x * inv; rr.y = o.y * inv; rr.z = o.z * inv; rr.w = o.w * inv;
        ((float4*)s_ao)[c] = rr;
    }
    __syncthreads();

    // ---------- Phase B: post pipeline ----------
    // Wo-proj: 128 outs, K=512. c5 = out quad (32), kg16 = K-group (16x32).
    // Single 32-deep load batch (128 VGPRs in flight).
    int c5   = t & 31;
    int kg16 = t >> 5;
    {
        const float4* WoR = (const float4*)(Wo + (size_t)layer * INNER * DIMM);
        int kkb = kg16 * 32;
        float4 w[32];
#pragma unroll
        for (int p = 0; p < 32; p++) w[p] = WoR[(kkb + p) * 32 + c5];
        float4 acc = {0, 0, 0, 0};
#pragma unroll
        for (int p = 0; p < 32; p++) fma4(acc, s_ao[kkb + p], w[p]);
        ((float4*)(s_part + kg16 * 128))[c5] = acc;
    }
    __syncthreads();
    float x = 0.0f;
    if (own) {
        x = bo[layer * DIMM + d];
#pragma unroll
        for (int g = 0; g < 16; g++) x += s_part[g * 128 + d];
    }

    // gated residual 1
    const float* Wg1_l = Wg1 + layer * 3 * DIMM;
    float texpr = own ? (x * Wg1_l[d] + res * Wg1_l[DIMM + d] + (x - res) * Wg1_l[2 * DIMM + d]) : 0.0f;
    float g1 = block_reduce_sum_8w(texpr, s_red);
    g1 = 1.0f / (1.0f + __expf(-g1));
    float n1 = x * g1 + res * (1.0f - g1);

    // LN2
    float m   = block_reduce_sum_8w(own ? n1 : 0.0f, s_red) * (1.0f / 128.0f);
    float df  = n1 - m;
    float var = block_reduce_sum_8w(own ? df * df : 0.0f, s_red) * (1.0f / 128.0f);
    float xn  = df * rsqrtf(var + 1e-5f) * ln2_g[layer * DIMM + d] + ln2_b[layer * DIMM + d];
    if (own) s_xn[d] = xn;
    __syncthreads();

    // FF1 + exact gelu: 512 outs, K=128. c7 = out quad (128), kg4 = K-group (4x32).
    int c7  = t & 127;
    int kg4 = t >> 7;
    {
        const float4* W1R = (const float4*)(W1 + (size_t)layer * DIMM * 4 * DIMM);
        int kkb = kg4 * 32;
        float4 w[32];
#pragma unroll
        for (int p = 0; p < 32; p++) w[p] = W1R[(kkb + p) * 128 + c7];
        float4 acc = {0, 0, 0, 0};
#pragma unroll
        for (int p = 0; p < 32; p++) fma4(acc, s_xn[kkb + p], w[p]);
        ((float4*)(s_part + kg4 * 512))[c7] = acc;
    }
    __syncthreads();
    {
        float a = b1[layer * 4 * DIMM + t];
#pragma unroll
        for (int g = 0; g < 4; g++) a += s_part[g * 512 + t];
        a = 0.5f * a * (1.0f + erff(a * 0.70710678f));
        s_h[t] = a;
    }
    __syncthreads();

    // FF2: 128 outs, K=512
    {
        const float4* W2R = (const float4*)(W2 + (size_t)layer * 4 * DIMM * DIMM);
        int kkb = kg16 * 32;
        float4 w[32];
#pragma unroll
        for (int p = 0; p < 32; p++) w[p] = W2R[(kkb + p) * 32 + c5];
        float4 acc = {0, 0, 0, 0};
#pragma unroll
        for (int p = 0; p < 32; p++) fma4(acc, s_h[kkb + p], w[p]);
        ((float4*)(s_part + kg16 * 128))[c5] = acc;
    }
    __syncthreads();
    float y = 0.0f;
    if (own) {
        y = b2[layer * DIMM + d];
#pragma unroll
        for (int g = 0; g < 16; g++) y += s_part[g * 128 + d];
    }

    // gated residual 2
    const float* Wg2_l = Wg2 + layer * 3 * DIMM;
    texpr = own ? (y * Wg2_l[d] + n1 * Wg2_l[DIMM + d] + (y - n1) * Wg2_l[2 * DIMM + d]) : 0.0f;
    float g2 = block_reduce_sum_8w(texpr, s_red);
    g2 = 1.0f / (1.0f + __expf(-g2));
    float n2 = y * g2 + n1 * (1.0f - g2);
    if (own) nodes[bn * DIMM + d] = n2;

    if (layer < DEPTH - 1) {
        ln_qkv_pf(own ? n2 : 0.0f, own, t, bn, layer + 1, ln1_g, ln1_b, Wq, bq, Wkv, bkv,
                  qb, kout, vout, s_xn, s_red, s_part);
    }
}

// Final: sum over nodes of (nodes @ Wlin + blin) -> scalar.
__global__ __launch_bounds__(256) void k_final(const float* nodes, const float* Wlin,
                                               const float* blin, float* out) {
    int t = threadIdx.x; // node index
    __shared__ float s_w[DIMM];
    if (t < DIMM) s_w[t] = Wlin[t];
    __syncthreads();
    float s = blin[0];
    const float4* nr = (const float4*)(nodes + t * DIMM);
#pragma unroll 8
    for (int q = 0; q < 32; q++) {
        float4 n = nr[q];
        s += n.x * s_w[4 * q] + n.y * s_w[4 * q + 1] + n.z * s_w[4 * q + 2] + n.w * s_w[4 * q + 3];
    }
#pragma unroll
    for (int off = 32; off > 0; off >>= 1) s += __shfl_xor(s, off, 64);
    __shared__ float sb[4];
    int wave = t >> 6, lane = t & 63;
    if (lane == 0) sb[wave] = s;
    __syncthreads();
    if (t == 0) out[0] = sb[0] + sb[1] + sb[2] + sb[3];
}

extern "C" void kernel_launch(void* const* d_in, const int* in_sizes, int n_in,
                              void* d_out, int out_size, void* d_ws, size_t ws_size,
                              hipStream_t stream) {
    const int*   indices = (const int*)d_in[0];
    const float* coords  = (const float*)d_in[1];
    const int*   bonds   = (const int*)d_in[2];
    const float* noise   = (const float*)d_in[3];
    const float* atom_emb= (const float*)d_in[4];
    const float* ln1_g   = (const float*)d_in[5];
    const float* ln1_b   = (const float*)d_in[6];
    const float* Wq      = (const float*)d_in[7];
    const float* bq      = (const float*)d_in[8];
    const float* Wkv     = (const float*)d_in[9];
    const float* bkv     = (const float*)d_in[10];
    const float* We      = (const float*)d_in[11];
    const float* be      = (const float*)d_in[12];
    const float* Wo      = (const float*)d_in[13];
    const float* bo      = (const float*)d_in[14];
    const float* Wg1     = (const float*)d_in[15];
    const float* ln2_g   = (const float*)d_in[16];
    const float* ln2_b   = (const float*)d_in[17];
    const float* W1      = (const float*)d_in[18];
    const float* b1      = (const float*)d_in[19];
    const float* W2      = (const float*)d_in[20];
    const float* b2      = (const float*)d_in[21];
    const float* Wg2     = (const float*)d_in[22];
    const float* Wlin    = (const float*)d_in[23];
    const float* blin    = (const float*)d_in[24];

    float* ws    = (float*)d_ws;
    float* nodes = ws;                       // 32768 floats
    float* qb    = nodes + BB * NN * DIMM;   // 131072 floats
    float* kb    = qb + KV_SLAB;             // 2 slabs
    float* vb    = kb + 2 * KV_SLAB;         // 2 slabs

    k_pre<<<BB * NN, 512, 0, stream>>>(indices, noise, atom_emb, ln1_g, ln1_b,
                                       Wq, bq, Wkv, bkv, nodes, qb, kb, vb);
    for (int l = 0; l < DEPTH; l++) {
        const float* kin = kb + (size_t)(l & 1) * KV_SLAB;
        const float* vin = vb + (size_t)(l & 1) * KV_SLAB;
        float* kout = kb + (size_t)((l + 1) & 1) * KV_SLAB;
        float* vout = vb + (size_t)((l + 1) & 1) * KV_SLAB;
        k_layer<<<BB * NN, 512, 0, stream>>>(l, coords, bonds, We, be,
                                             qb, kin, vin, kout, vout,
                                             Wo, bo, Wg1, ln2_g, ln2_b, W1, b1, W2, b2,
                                             Wg2, ln1_g, ln1_b, Wq, bq, Wkv, bkv, nodes);
    }
    k_final<<<1, 256, 0, stream>>>(nodes, Wlin, blin, (float*)d_out);
}